// Round 1
// baseline (389.401 us; speedup 1.0000x reference)
//
#include <hip/hip_runtime.h>

#define TB 128

// ---------------- LDS layout (float offsets) ----------------
// Frontend:
#define XBUF   0        // 64*128 = 8192 (x staging)
#define XSP    8192     // 16*199 = 3184 (spatial-conv out, zero-padded for temporal conv)
#define WS     11376    // 16*65  = 1040 (conv_s weights)
#define SCA    12416    // 16 fused scale
#define SCC    12432    // 16 fused const
#define LDS_TOT 12448   // 49792 B -> 3 blocks/CU
// Aliases inside XBUF region (valid after stage 1):
#define YEL    0        // 16*133 = 2128 (elu output)
#define PROJW  2128     // 16*81  = 1296
#define PROJB  3424     // 16
#define POOLED 3440     // 16*25 = 400
#define TOKP   3840     // 80
#define CLSB   3920     // 16
#define PEB    3936     // 96
// WT aliases WS region (valid after stage 1):
#define WT     11376    // 8*63 = 504
// Transformer aliases (valid after stage 5):
#define WQKV   0        // 192*20 = 3840
#define BQKV   3840     // 192
#define WOUT   4032     // 16*68 = 1088
#define BOUT   5120     // 16
#define WM1    5136     // 32*20 = 640
#define BM1    5776     // 32
#define WM2    5808     // 16*36 = 576
#define BM2    6384     // 16
#define LN1Gs  6400     // 16
#define LN1Bs  6416     // 16
#define LN2Gs  6432     // 16
#define LN2Bs  6448     // 16
#define H1S    6464     // 6*20 = 120
#define QKVS   6584     // 6*193 = 1158
#define OATT   7742     // 6*65 = 390
#define MHS    8132     // 6*36 = 216  (ends 8348 <= 12448)

extern "C" __global__ __launch_bounds__(TB)
void eegnet_vit_fused(
    const float* __restrict__ x,
    const float* __restrict__ conv_t_w, const float* __restrict__ conv_t_b,
    const float* __restrict__ bn1_g, const float* __restrict__ bn1_b,
    const float* __restrict__ bn1_m, const float* __restrict__ bn1_v,
    const float* __restrict__ conv_s_w, const float* __restrict__ conv_s_b,
    const float* __restrict__ bn2_g, const float* __restrict__ bn2_b,
    const float* __restrict__ bn2_m, const float* __restrict__ bn2_v,
    const float* __restrict__ proj_w, const float* __restrict__ proj_b,
    const float* __restrict__ cls_token, const float* __restrict__ pe,
    const float* __restrict__ qkv_w, const float* __restrict__ qkv_b,
    const float* __restrict__ out_w, const float* __restrict__ out_b,
    const float* __restrict__ ln1_g, const float* __restrict__ ln1_b,
    const float* __restrict__ ln2_g, const float* __restrict__ ln2_b,
    const float* __restrict__ mlp_w1, const float* __restrict__ mlp_b1,
    const float* __restrict__ mlp_w2, const float* __restrict__ mlp_b2,
    const float* __restrict__ head_ln_g, const float* __restrict__ head_ln_b,
    const float* __restrict__ head_w, const float* __restrict__ head_b,
    float* __restrict__ out)
{
    __shared__ float sm[LDS_TOT];
    const int b   = blockIdx.x;
    const int tid = threadIdx.x;

    // ================= stage 0: stage x, conv_s weights, fused BN affines ==========
    {
        const float* xb = x + (size_t)b * (64 * 125);
        for (int i = tid; i < 8000; i += TB) {
            int c = i / 125, t = i - c * 125;
            sm[XBUF + c * 128 + t] = xb[i];
        }
        for (int i = tid; i < 1024; i += TB)
            sm[WS + (i >> 6) * 65 + (i & 63)] = conv_s_w[i];
        for (int i = tid; i < 16 * 199; i += TB) sm[XSP + i] = 0.f;
        if (tid < 16) {
            int o = tid, g = o >> 1;
            float s1 = bn1_g[g] * rsqrtf(bn1_v[g] + 1e-5f);
            float b1 = (conv_t_b[g] - bn1_m[g]) * s1 + bn1_b[g];
            float s2 = bn2_g[o] * rsqrtf(bn2_v[o] + 1e-5f);
            float ssum = 0.f;
            for (int c = 0; c < 64; ++c) ssum += conv_s_w[o * 64 + c];
            sm[SCA + o] = s1 * s2;
            sm[SCC + o] = (b1 * ssum + conv_s_b[o] - bn2_m[o]) * s2 + bn2_b[o];
        }
    }
    __syncthreads();

    // ================= stage 1: spatial conv xs[o][t] = sum_c ws[o][c]*x[c][t] =====
    {
        const int o = tid & 15, tg = tid >> 4, t0 = tg * 16;
        float acc[16];
        #pragma unroll
        for (int j = 0; j < 16; ++j) acc[j] = 0.f;
        for (int c = 0; c < 64; ++c) {
            float w = sm[WS + o * 65 + c];
            const float4* xp = reinterpret_cast<const float4*>(&sm[XBUF + c * 128 + t0]);
            #pragma unroll
            for (int q = 0; q < 4; ++q) {
                float4 v = xp[q];
                acc[q * 4 + 0] += w * v.x;
                acc[q * 4 + 1] += w * v.y;
                acc[q * 4 + 2] += w * v.z;
                acc[q * 4 + 3] += w * v.w;
            }
        }
        #pragma unroll
        for (int j = 0; j < 16; ++j) {
            int t = t0 + j;
            if (t < 125) sm[XSP + o * 199 + 32 + t] = acc[j];
        }
    }
    __syncthreads();

    // stage 1.5: stage temporal weights + projection params into freed regions
    for (int i = tid; i < 504; i += TB) sm[WT + i] = conv_t_w[i];
    for (int i = tid; i < 1280; i += TB) {
        int dd = i / 80, f = i - dd * 80;
        sm[PROJW + dd * 81 + f] = proj_w[i];
    }
    if (tid < 16) sm[PROJB + tid] = proj_b[tid];
    if (tid < 16) sm[CLSB + tid] = cls_token[tid];
    if (tid < 96) sm[PEB + tid] = pe[tid];
    __syncthreads();

    // ================= stage 2: temporal conv + fused BN + ELU ======================
    {
        const int o = tid & 15, tg = tid >> 4, t0 = tg * 16, g = o >> 1;
        float acc[16];
        #pragma unroll
        for (int j = 0; j < 16; ++j) acc[j] = 0.f;
        const float* xs  = &sm[XSP + o * 199 + 1 + t0];
        const float* wtp = &sm[WT + g * 63];
        int k = 0;
        for (; k + 4 <= 63; k += 4) {           // 15 quads (k=0..59)
            float w0 = wtp[k], w1 = wtp[k + 1], w2 = wtp[k + 2], w3 = wtp[k + 3];
            float xw[19];
            #pragma unroll
            for (int i2 = 0; i2 < 19; ++i2) xw[i2] = xs[k + i2];
            #pragma unroll
            for (int j = 0; j < 16; ++j)
                acc[j] += w0 * xw[j] + w1 * xw[j + 1] + w2 * xw[j + 2] + w3 * xw[j + 3];
        }
        for (; k < 63; ++k) {                    // k = 60,61,62
            float w = wtp[k];
            #pragma unroll
            for (int j = 0; j < 16; ++j) acc[j] += w * xs[k + j];
        }
        float sa = sm[SCA + o], cc = sm[SCC + o];
        #pragma unroll
        for (int j = 0; j < 16; ++j) {
            int t = t0 + j;
            if (t < 125) {
                float v = acc[j] * sa + cc;
                sm[YEL + o * 133 + t] = v > 0.f ? v : (__expf(v) - 1.f);
            }
        }
    }
    __syncthreads();

    // ================= stage 3: avg pool (1,5) ======================================
    for (int i = tid; i < 400; i += TB) {
        int o = i / 25, jj = i - o * 25;
        const float* yp = &sm[YEL + o * 133 + jj * 5];
        sm[POOLED + o * 25 + jj] = (yp[0] + yp[1] + yp[2] + yp[3] + yp[4]) * 0.2f;
    }
    __syncthreads();

    // ================= stage 4: token projection (5,80)@(80,16) =====================
    if (tid < 80) {
        int p = tid >> 4, dd = tid & 15;
        float acc = sm[PROJB + dd];
        #pragma unroll
        for (int ch = 0; ch < 16; ++ch)
            #pragma unroll
            for (int q = 0; q < 5; ++q)
                acc += sm[POOLED + ch * 25 + p * 5 + q] * sm[PROJW + dd * 81 + ch * 5 + q];
        sm[TOKP + p * 16 + dd] = acc;
    }
    __syncthreads();

    // ================= stage 5: cls/pe -> z registers ===============================
    const int t6 = tid >> 4, d16 = tid & 15;
    float zreg = 0.f;
    if (tid < 96) {
        float base = (t6 == 0) ? sm[CLSB + d16] : sm[TOKP + (t6 - 1) * 16 + d16];
        zreg = base + sm[PEB + t6 * 16 + d16];
    }
    __syncthreads();   // transformer staging below overwrites all frontend LDS

    // ================= transformer: 6 layers ========================================
    for (int li = 0; li < 6; ++li) {
        // --- stage layer weights into LDS (padded strides) ---
        for (int i = tid; i < 3072; i += TB) {
            int j = i >> 4, d = i & 15;
            sm[WQKV + j * 20 + d] = qkv_w[li * 3072 + i];
        }
        for (int i = tid; i < 192; i += TB) sm[BQKV + i] = qkv_b[li * 192 + i];
        for (int i = tid; i < 1024; i += TB) {
            int dd = i >> 6, j = i & 63;
            sm[WOUT + dd * 68 + j] = out_w[li * 1024 + i];
        }
        for (int i = tid; i < 512; i += TB) {
            int u = i >> 4, d = i & 15;
            sm[WM1 + u * 20 + d] = mlp_w1[li * 512 + i];
        }
        for (int i = tid; i < 512; i += TB) {
            int dd = i >> 5, u = i & 31;
            sm[WM2 + dd * 36 + u] = mlp_w2[li * 512 + i];
        }
        if (tid < 16) {
            sm[BOUT + tid]  = out_b[li * 16 + tid];
            sm[BM2 + tid]   = mlp_b2[li * 16 + tid];
            sm[LN1Gs + tid] = ln1_g[li * 16 + tid];
            sm[LN1Bs + tid] = ln1_b[li * 16 + tid];
            sm[LN2Gs + tid] = ln2_g[li * 16 + tid];
            sm[LN2Bs + tid] = ln2_b[li * 16 + tid];
        }
        if (tid >= 16 && tid < 48) sm[BM1 + tid - 16] = mlp_b1[li * 32 + tid - 16];
        __syncthreads();

        // --- Phase A: LN1 (shuffle reduce within 16-lane dim groups) ---
        if (tid < 96) {
            float s = zreg, q = zreg * zreg;
            #pragma unroll
            for (int off = 8; off >= 1; off >>= 1) {
                s += __shfl_xor(s, off, 16);
                q += __shfl_xor(q, off, 16);
            }
            float mean = s * 0.0625f;
            float var  = q * 0.0625f - mean * mean;
            float rst  = rsqrtf(var + 1e-5f);
            sm[H1S + t6 * 20 + d16] = (zreg - mean) * rst * sm[LN1Gs + d16] + sm[LN1Bs + d16];
        }
        __syncthreads();

        // --- Phase B: qkv = h1 @ Wqkv^T + b  (each lane: 12 output cols, own token) ---
        if (tid < 96) {
            float hrow[16];
            const float4* hp = reinterpret_cast<const float4*>(&sm[H1S + t6 * 20]);
            #pragma unroll
            for (int q4 = 0; q4 < 4; ++q4) {
                float4 v = hp[q4];
                hrow[q4 * 4 + 0] = v.x; hrow[q4 * 4 + 1] = v.y;
                hrow[q4 * 4 + 2] = v.z; hrow[q4 * 4 + 3] = v.w;
            }
            #pragma unroll
            for (int r = 0; r < 12; ++r) {
                int j = d16 + r * 16;
                float acc = sm[BQKV + j];
                const float4* wp = reinterpret_cast<const float4*>(&sm[WQKV + j * 20]);
                #pragma unroll
                for (int q4 = 0; q4 < 4; ++q4) {
                    float4 w = wp[q4];
                    acc += hrow[q4 * 4 + 0] * w.x + hrow[q4 * 4 + 1] * w.y
                         + hrow[q4 * 4 + 2] * w.z + hrow[q4 * 4 + 3] * w.w;
                }
                sm[QKVS + t6 * 193 + j] = acc;
            }
        }
        __syncthreads();

        // --- Phase C: attention (lane = (head, query-token), 48 lanes) ---
        if (tid < 48) {
            int h = tid & 7, s = tid >> 3;
            float qv[8];
            #pragma unroll
            for (int e = 0; e < 8; ++e) qv[e] = sm[QKVS + s * 193 + h * 8 + e];
            float sc[6];
            #pragma unroll
            for (int u = 0; u < 6; ++u) {
                float a = 0.f;
                #pragma unroll
                for (int e = 0; e < 8; ++e) a += qv[e] * sm[QKVS + u * 193 + 64 + h * 8 + e];
                sc[u] = a * 0.35355339059327373f;   // QK^-0.5
            }
            float mx = sc[0];
            #pragma unroll
            for (int u = 1; u < 6; ++u) mx = fmaxf(mx, sc[u]);
            float ssum = 0.f;
            #pragma unroll
            for (int u = 0; u < 6; ++u) { sc[u] = __expf(sc[u] - mx); ssum += sc[u]; }
            float inv = 1.f / ssum;
            #pragma unroll
            for (int u = 0; u < 6; ++u) sc[u] *= inv;
            #pragma unroll
            for (int e = 0; e < 8; ++e) {
                float a = 0.f;
                #pragma unroll
                for (int u = 0; u < 6; ++u) a += sc[u] * sm[QKVS + u * 193 + 128 + h * 8 + e];
                sm[OATT + s * 65 + h * 8 + e] = a;
            }
        }
        __syncthreads();

        // --- Phase D: out projection + residual ---
        if (tid < 96) {
            float acc = sm[BOUT + d16];
            const float4* wp = reinterpret_cast<const float4*>(&sm[WOUT + d16 * 68]);
            const float* op = &sm[OATT + t6 * 65];
            #pragma unroll
            for (int q4 = 0; q4 < 16; ++q4) {
                float4 w = wp[q4];
                acc += op[q4 * 4 + 0] * w.x + op[q4 * 4 + 1] * w.y
                     + op[q4 * 4 + 2] * w.z + op[q4 * 4 + 3] * w.w;
            }
            zreg += acc;
        }

        // --- Phase E: LN2 (register-only inputs; safe without extra barrier) ---
        if (tid < 96) {
            float s = zreg, q = zreg * zreg;
            #pragma unroll
            for (int off = 8; off >= 1; off >>= 1) {
                s += __shfl_xor(s, off, 16);
                q += __shfl_xor(q, off, 16);
            }
            float mean = s * 0.0625f;
            float var  = q * 0.0625f - mean * mean;
            float rst  = rsqrtf(var + 1e-5f);
            sm[H1S + t6 * 20 + d16] = (zreg - mean) * rst * sm[LN2Gs + d16] + sm[LN2Bs + d16];
        }
        __syncthreads();

        // --- Phase F: mlp1 + exact GELU (erf, A&S 7.1.26) ---
        if (tid < 96) {
            float hrow[16];
            const float4* hp = reinterpret_cast<const float4*>(&sm[H1S + t6 * 20]);
            #pragma unroll
            for (int q4 = 0; q4 < 4; ++q4) {
                float4 v = hp[q4];
                hrow[q4 * 4 + 0] = v.x; hrow[q4 * 4 + 1] = v.y;
                hrow[q4 * 4 + 2] = v.z; hrow[q4 * 4 + 3] = v.w;
            }
            #pragma unroll
            for (int r = 0; r < 2; ++r) {
                int u = d16 + r * 16;
                float acc = sm[BM1 + u];
                const float4* wp = reinterpret_cast<const float4*>(&sm[WM1 + u * 20]);
                #pragma unroll
                for (int q4 = 0; q4 < 4; ++q4) {
                    float4 w = wp[q4];
                    acc += hrow[q4 * 4 + 0] * w.x + hrow[q4 * 4 + 1] * w.y
                         + hrow[q4 * 4 + 2] * w.z + hrow[q4 * 4 + 3] * w.w;
                }
                float xa = fabsf(acc) * 0.70710678118654752f;
                float tt = 1.f / (1.f + 0.3275911f * xa);
                float poly = tt * (0.254829592f + tt * (-0.284496736f + tt * (1.421413741f
                           + tt * (-1.453152027f + tt * 1.061405429f))));
                float erfv = 1.f - poly * __expf(-xa * xa);
                erfv = acc >= 0.f ? erfv : -erfv;
                sm[MHS + t6 * 36 + u] = 0.5f * acc * (1.f + erfv);
            }
        }
        __syncthreads();

        // --- Phase G: mlp2 + residual ---
        if (tid < 96) {
            float acc = sm[BM2 + d16];
            const float4* wp = reinterpret_cast<const float4*>(&sm[WM2 + d16 * 36]);
            const float* mp = &sm[MHS + t6 * 36];
            #pragma unroll
            for (int q4 = 0; q4 < 8; ++q4) {
                float4 w = wp[q4];
                acc += mp[q4 * 4 + 0] * w.x + mp[q4 * 4 + 1] * w.y
                     + mp[q4 * 4 + 2] * w.z + mp[q4 * 4 + 3] * w.w;
            }
            zreg += acc;
        }
        __syncthreads();   // protect weight buffers before next layer's staging
    }

    // ================= head: LN(cls) -> 2-way linear -> softmax =====================
    if (tid < 16) {
        float s = zreg, q = zreg * zreg;
        #pragma unroll
        for (int off = 8; off >= 1; off >>= 1) {
            s += __shfl_xor(s, off, 16);
            q += __shfl_xor(q, off, 16);
        }
        float mean = s * 0.0625f;
        float var  = q * 0.0625f - mean * mean;
        float rst  = rsqrtf(var + 1e-5f);
        float cv   = (zreg - mean) * rst * head_ln_g[d16] + head_ln_b[d16];
        float p0 = cv * head_w[d16];
        float p1 = cv * head_w[16 + d16];
        #pragma unroll
        for (int off = 8; off >= 1; off >>= 1) {
            p0 += __shfl_xor(p0, off, 16);
            p1 += __shfl_xor(p1, off, 16);
        }
        if (tid == 0) {
            float l0 = p0 + head_b[0], l1 = p1 + head_b[1];
            float mx = fmaxf(l0, l1);
            float e0 = __expf(l0 - mx), e1 = __expf(l1 - mx);
            float inv = 1.f / (e0 + e1);
            out[b * 2 + 0] = e0 * inv;
            out[b * 2 + 1] = e1 * inv;
        }
    }
}

extern "C" void kernel_launch(void* const* d_in, const int* in_sizes, int n_in,
                              void* d_out, int out_size, void* d_ws, size_t ws_size,
                              hipStream_t stream) {
    (void)n_in; (void)d_ws; (void)ws_size; (void)out_size;
    const float* a0  = (const float*)d_in[0];   // x
    const float* a1  = (const float*)d_in[1];   // conv_t_w
    const float* a2  = (const float*)d_in[2];   // conv_t_b
    const float* a3  = (const float*)d_in[3];   // bn1_g
    const float* a4  = (const float*)d_in[4];   // bn1_b
    const float* a5  = (const float*)d_in[5];   // bn1_m
    const float* a6  = (const float*)d_in[6];   // bn1_v
    const float* a7  = (const float*)d_in[7];   // conv_s_w
    const float* a8  = (const float*)d_in[8];   // conv_s_b
    const float* a9  = (const float*)d_in[9];   // bn2_g
    const float* a10 = (const float*)d_in[10];  // bn2_b
    const float* a11 = (const float*)d_in[11];  // bn2_m
    const float* a12 = (const float*)d_in[12];  // bn2_v
    const float* a13 = (const float*)d_in[13];  // proj_w
    const float* a14 = (const float*)d_in[14];  // proj_b
    const float* a15 = (const float*)d_in[15];  // cls_token
    const float* a16 = (const float*)d_in[16];  // pe
    const float* a17 = (const float*)d_in[17];  // qkv_w
    const float* a18 = (const float*)d_in[18];  // qkv_b
    const float* a19 = (const float*)d_in[19];  // out_w
    const float* a20 = (const float*)d_in[20];  // out_b
    const float* a21 = (const float*)d_in[21];  // ln1_g
    const float* a22 = (const float*)d_in[22];  // ln1_b
    const float* a23 = (const float*)d_in[23];  // ln2_g
    const float* a24 = (const float*)d_in[24];  // ln2_b
    const float* a25 = (const float*)d_in[25];  // mlp_w1
    const float* a26 = (const float*)d_in[26];  // mlp_b1
    const float* a27 = (const float*)d_in[27];  // mlp_w2
    const float* a28 = (const float*)d_in[28];  // mlp_b2
    const float* a29 = (const float*)d_in[29];  // head_ln_g
    const float* a30 = (const float*)d_in[30];  // head_ln_b
    const float* a31 = (const float*)d_in[31];  // head_w
    const float* a32 = (const float*)d_in[32];  // head_b

    int Bn = in_sizes[0] / (64 * 125);          // 2048
    eegnet_vit_fused<<<Bn, TB, 0, stream>>>(
        a0, a1, a2, a3, a4, a5, a6, a7, a8, a9, a10, a11, a12, a13, a14, a15, a16,
        a17, a18, a19, a20, a21, a22, a23, a24, a25, a26, a27, a28, a29, a30, a31, a32,
        (float*)d_out);
}

// Round 2
// 250.098 us; speedup vs baseline: 1.5570x; 1.5570x over previous
//
#include <hip/hip_runtime.h>

#define TB 64

// Wave-synchronous: DS ops complete in order within a wave (ISA guarantee).
// These fences only stop the COMPILER from reordering/caching LDS accesses.
#define WAVE_SYNC() do { asm volatile("" ::: "memory"); \
                         __builtin_amdgcn_wave_barrier(); \
                         asm volatile("" ::: "memory"); } while (0)

// ---------------- LDS layout (float offsets), total 3664 floats = 14.3 KB ----
#define XSP    0        // 16 rows x 196 (spatial-conv out, zero-padded both sides)
// transformer scratch aliases XSP (frontend dead by then):
#define H1     0        // 6 x 20
#define QKV    128      // 6 x 196 (q at +0, k at +64, v at +128 within row)
#define OATT   1312     // 6 x 68
#define MHS    1728     // 6 x 36   (ends 1944 < 3136)
#define POOL   3136     // 16 x 28
#define TOK    3584     // 80
#define LDS_TOT 3664

__device__ __forceinline__ float ln_norm16(float z, float g, float bb) {
    float s = z, q = z * z;
    #pragma unroll
    for (int off = 8; off >= 1; off >>= 1) {
        s += __shfl_xor(s, off, 16);
        q += __shfl_xor(q, off, 16);
    }
    float mean = s * 0.0625f;
    float var  = q * 0.0625f - mean * mean;
    return (z - mean) * rsqrtf(var + 1e-5f) * g + bb;
}

__device__ __forceinline__ float gelu_exact(float a) {
    float xa = fabsf(a) * 0.70710678118654752f;
    float tt = 1.f / (1.f + 0.3275911f * xa);
    float poly = tt * (0.254829592f + tt * (-0.284496736f + tt * (1.421413741f
               + tt * (-1.453152027f + tt * 1.061405429f))));
    float erfv = 1.f - poly * __expf(-xa * xa);
    erfv = a >= 0.f ? erfv : -erfv;
    return 0.5f * a * (1.f + erfv);
}

__device__ __forceinline__ float dot16(const float* h, float4 w0, float4 w1,
                                       float4 w2, float4 w3) {
    return h[0]*w0.x + h[1]*w0.y + h[2]*w0.z + h[3]*w0.w
         + h[4]*w1.x + h[5]*w1.y + h[6]*w1.z + h[7]*w1.w
         + h[8]*w2.x + h[9]*w2.y + h[10]*w2.z + h[11]*w2.w
         + h[12]*w3.x + h[13]*w3.y + h[14]*w3.z + h[15]*w3.w;
}

extern "C" __global__ __launch_bounds__(TB, 2)
void eegnet_vit_fused(
    const float* __restrict__ x,
    const float* __restrict__ conv_t_w, const float* __restrict__ conv_t_b,
    const float* __restrict__ bn1_g, const float* __restrict__ bn1_b,
    const float* __restrict__ bn1_m, const float* __restrict__ bn1_v,
    const float* __restrict__ conv_s_w, const float* __restrict__ conv_s_b,
    const float* __restrict__ bn2_g, const float* __restrict__ bn2_b,
    const float* __restrict__ bn2_m, const float* __restrict__ bn2_v,
    const float* __restrict__ proj_w, const float* __restrict__ proj_b,
    const float* __restrict__ cls_token, const float* __restrict__ pe,
    const float* __restrict__ qkv_w, const float* __restrict__ qkv_b,
    const float* __restrict__ out_w, const float* __restrict__ out_b,
    const float* __restrict__ ln1_g, const float* __restrict__ ln1_b,
    const float* __restrict__ ln2_g, const float* __restrict__ ln2_b,
    const float* __restrict__ mlp_w1, const float* __restrict__ mlp_b1,
    const float* __restrict__ mlp_w2, const float* __restrict__ mlp_b2,
    const float* __restrict__ head_ln_g, const float* __restrict__ head_ln_b,
    const float* __restrict__ head_w, const float* __restrict__ head_b,
    float* __restrict__ out)
{
    __shared__ __align__(16) float sm[LDS_TOT];
    const int b    = blockIdx.x;
    const int lane = threadIdx.x;

    // ---------- zero the padded conv buffer ----------
    {
        float4 z4 = {0.f, 0.f, 0.f, 0.f};
        float4* s4 = reinterpret_cast<float4*>(sm);
        for (int i = lane; i < 784; i += TB) s4[i] = z4;   // 3136 floats
    }

    // ---------- stage 1: spatial conv, x read coalesced from global ----------
    // xs[o][t] = sum_c ws[o][c] * x[c][t];  lane covers t=lane and t=64+lane
    {
        const float* xb = x + (size_t)b * 8000;
        const int l2 = min(lane, 60);                      // clamp OOB tail
        float a0[16], a1[16];
        #pragma unroll
        for (int o = 0; o < 16; ++o) { a0[o] = 0.f; a1[o] = 0.f; }
        #pragma unroll 8
        for (int c = 0; c < 64; ++c) {
            float xv0 = __builtin_nontemporal_load(xb + c * 125 + lane);
            float xv1 = __builtin_nontemporal_load(xb + c * 125 + 64 + l2);
            #pragma unroll
            for (int o = 0; o < 16; ++o) {
                float w = conv_s_w[o * 64 + c];            // wave-uniform -> s_load
                a0[o] += w * xv0;
                a1[o] += w * xv1;
            }
        }
        #pragma unroll
        for (int o = 0; o < 16; ++o) {
            sm[XSP + o * 196 + 32 + lane] = a0[o];
            if (lane < 61) sm[XSP + o * 196 + 96 + lane] = a1[o];
        }
    }

    // ---------- fused BN constants + temporal weights (per-lane, o = lane&15) ----
    const int oo = lane & 15, qg = lane >> 4, gg = oo >> 1;
    float sa, cc;
    {
        float s1 = bn1_g[gg] * rsqrtf(bn1_v[gg] + 1e-5f);
        float b1 = (conv_t_b[gg] - bn1_m[gg]) * s1 + bn1_b[gg];
        float s2 = bn2_g[oo] * rsqrtf(bn2_v[oo] + 1e-5f);
        float ssum = 0.f;
        const float4* csw = reinterpret_cast<const float4*>(conv_s_w + oo * 64);
        #pragma unroll
        for (int i = 0; i < 16; ++i) {
            float4 v = csw[i];
            ssum += v.x + v.y + v.z + v.w;
        }
        sa = s1 * s2;
        cc = (b1 * ssum + conv_s_b[oo] - bn2_m[oo]) * s2 + bn2_b[oo];
    }
    float wt[63];
    #pragma unroll
    for (int k = 0; k < 63; ++k) wt[k] = conv_t_w[gg * 63 + k];

    WAVE_SYNC();   // spatial writes -> temporal reads

    // ---------- stage 2: temporal conv + BN + ELU + avg-pool, all in regs ------
    // lane (oo, qg) produces pooled[oo][j], j = qg*7 .. (7,7,7,4 per group)
    #pragma unroll 1
    for (int jj = 0; jj < 7; ++jj) {
        int j  = qg * 7 + jj;
        int jc = min(j, 24);
        int base = XSP + oo * 196 + 5 * jc + 1;
        float acc5[5] = {0.f, 0.f, 0.f, 0.f, 0.f};
        #pragma unroll
        for (int m = 0; m < 67; ++m) {
            float xv = sm[base + m];
            #pragma unroll
            for (int u = 0; u < 5; ++u)
                if (u <= m && m - u <= 62) acc5[u] += wt[m - u] * xv;
        }
        float psum = 0.f;
        #pragma unroll
        for (int u = 0; u < 5; ++u) {
            float v = acc5[u] * sa + cc;
            psum += (v > 0.f) ? v : (__expf(v) - 1.f);
        }
        if (j == jc) sm[POOL + oo * 28 + j] = psum * 0.2f;
    }

    WAVE_SYNC();   // pooled writes -> proj reads

    // ---------- stage 3: token projection (5,80)@(80,16)^T ----------
    #pragma unroll
    for (int pass = 0; pass < 2; ++pass) {
        int oi = (pass == 0) ? lane : (64 + lane);
        int p = oi >> 4, dd = oi & 15;
        int pc = min(p, 4);
        bool act = (pass == 0) || (lane < 16);
        float acc = proj_b[dd];
        const float4* wp = reinterpret_cast<const float4*>(proj_w + dd * 80);
        #pragma unroll
        for (int i = 0; i < 20; ++i) {
            float4 w4 = wp[i];
            acc += w4.x * sm[POOL + ((4*i+0)/5) * 28 + pc * 5 + ((4*i+0)%5)];
            acc += w4.y * sm[POOL + ((4*i+1)/5) * 28 + pc * 5 + ((4*i+1)%5)];
            acc += w4.z * sm[POOL + ((4*i+2)/5) * 28 + pc * 5 + ((4*i+2)%5)];
            acc += w4.w * sm[POOL + ((4*i+3)/5) * 28 + pc * 5 + ((4*i+3)%5)];
        }
        if (act) sm[TOK + pc * 16 + dd] = acc;
    }

    WAVE_SYNC();   // tok writes -> z init reads

    // ---------- z init: tokens 0..3 in zA (all lanes), 4..5 in zB (dup'd) -------
    const int tA = lane >> 4, d16 = lane & 15;
    const int tB = 4 + ((lane >> 4) & 1);      // lanes 32-63 duplicate 0-31 exactly
    float zA = ((tA == 0) ? cls_token[d16] : sm[TOK + (tA - 1) * 16 + d16])
             + pe[tA * 16 + d16];
    float zB = sm[TOK + (tB - 1) * 16 + d16] + pe[tB * 16 + d16];

    // ---------- transformer: 6 layers, zero barriers, weights from global -------
    #pragma unroll 1
    for (int li = 0; li < 6; ++li) {
        const float* qw  = qkv_w  + li * 3072;
        const float* qb2 = qkv_b  + li * 192;
        const float* ow  = out_w  + li * 1024;
        const float* w1  = mlp_w1 + li * 512;
        const float* w2  = mlp_w2 + li * 512;

        // --- LN1 -> H1 ---
        {
            float g = ln1_g[li * 16 + d16], bb = ln1_b[li * 16 + d16];
            sm[H1 + tA * 20 + d16] = ln_norm16(zA, g, bb);
            sm[H1 + tB * 20 + d16] = ln_norm16(zB, g, bb);   // dup write, same value
        }
        WAVE_SYNC();

        float hrA[16], hrB[16];
        {
            const float4* pA = reinterpret_cast<const float4*>(&sm[H1 + tA * 20]);
            const float4* pB = reinterpret_cast<const float4*>(&sm[H1 + tB * 20]);
            #pragma unroll
            for (int i = 0; i < 4; ++i) {
                float4 va = pA[i], vb = pB[i];
                hrA[4*i+0] = va.x; hrA[4*i+1] = va.y; hrA[4*i+2] = va.z; hrA[4*i+3] = va.w;
                hrB[4*i+0] = vb.x; hrB[4*i+1] = vb.y; hrB[4*i+2] = vb.z; hrB[4*i+3] = vb.w;
            }
        }

        // --- qkv: lane computes cols j = d16+16r for its two tokens ---
        #pragma unroll 2
        for (int r = 0; r < 12; ++r) {
            int j = d16 + 16 * r;
            const float4* wp = reinterpret_cast<const float4*>(qw + j * 16);
            float4 w0 = wp[0], w1_ = wp[1], w2_ = wp[2], w3_ = wp[3];
            float bb = qb2[j];
            float aA = bb + dot16(hrA, w0, w1_, w2_, w3_);
            float aB = bb + dot16(hrB, w0, w1_, w2_, w3_);
            sm[QKV + tA * 196 + j] = aA;
            sm[QKV + tB * 196 + j] = aB;                     // dup write, same value
        }
        WAVE_SYNC();

        // --- attention: lane = (head h, query s), 48 active ---
        if (lane < 48) {
            int h = lane & 7, s = lane >> 3;
            const float4* qp = reinterpret_cast<const float4*>(&sm[QKV + s * 196 + h * 8]);
            float4 q0 = qp[0], q1 = qp[1];
            float sc[6];
            #pragma unroll
            for (int u = 0; u < 6; ++u) {
                const float4* kp = reinterpret_cast<const float4*>(&sm[QKV + u * 196 + 64 + h * 8]);
                float4 k0 = kp[0], k1 = kp[1];
                sc[u] = (q0.x*k0.x + q0.y*k0.y + q0.z*k0.z + q0.w*k0.w
                       + q1.x*k1.x + q1.y*k1.y + q1.z*k1.z + q1.w*k1.w)
                       * 0.35355339059327373f;
            }
            float mx = sc[0];
            #pragma unroll
            for (int u = 1; u < 6; ++u) mx = fmaxf(mx, sc[u]);
            float ssum = 0.f;
            #pragma unroll
            for (int u = 0; u < 6; ++u) { sc[u] = __expf(sc[u] - mx); ssum += sc[u]; }
            float inv = 1.f / ssum;
            float o0 = 0.f, o1 = 0.f, o2 = 0.f, o3 = 0.f,
                  o4 = 0.f, o5 = 0.f, o6 = 0.f, o7 = 0.f;
            #pragma unroll
            for (int u = 0; u < 6; ++u) {
                const float4* vp = reinterpret_cast<const float4*>(&sm[QKV + u * 196 + 128 + h * 8]);
                float4 v0 = vp[0], v1 = vp[1];
                float a = sc[u] * inv;
                o0 += a * v0.x; o1 += a * v0.y; o2 += a * v0.z; o3 += a * v0.w;
                o4 += a * v1.x; o5 += a * v1.y; o6 += a * v1.z; o7 += a * v1.w;
            }
            *reinterpret_cast<float4*>(&sm[OATT + s * 68 + h * 8    ]) = float4{o0, o1, o2, o3};
            *reinterpret_cast<float4*>(&sm[OATT + s * 68 + h * 8 + 4]) = float4{o4, o5, o6, o7};
        }
        WAVE_SYNC();

        // --- out projection + residual (w row reused for both tokens) ---
        {
            const float4* wop = reinterpret_cast<const float4*>(ow + d16 * 64);
            const float4* oaA = reinterpret_cast<const float4*>(&sm[OATT + tA * 68]);
            const float4* oaB = reinterpret_cast<const float4*>(&sm[OATT + tB * 68]);
            float bb = out_b[li * 16 + d16];
            float aA = bb, aB = bb;
            #pragma unroll 4
            for (int i = 0; i < 16; ++i) {
                float4 w = wop[i];
                float4 va = oaA[i], vb = oaB[i];
                aA += va.x*w.x + va.y*w.y + va.z*w.z + va.w*w.w;
                aB += vb.x*w.x + vb.y*w.y + vb.z*w.z + vb.w*w.w;
            }
            zA += aA;
            zB += aB;
        }

        // --- LN2 -> H1 (WAR on H1 safe: program order + in-order DS pipe) ---
        {
            float g = ln2_g[li * 16 + d16], bb = ln2_b[li * 16 + d16];
            sm[H1 + tA * 20 + d16] = ln_norm16(zA, g, bb);
            sm[H1 + tB * 20 + d16] = ln_norm16(zB, g, bb);
        }
        WAVE_SYNC();

        {
            const float4* pA = reinterpret_cast<const float4*>(&sm[H1 + tA * 20]);
            const float4* pB = reinterpret_cast<const float4*>(&sm[H1 + tB * 20]);
            #pragma unroll
            for (int i = 0; i < 4; ++i) {
                float4 va = pA[i], vb = pB[i];
                hrA[4*i+0] = va.x; hrA[4*i+1] = va.y; hrA[4*i+2] = va.z; hrA[4*i+3] = va.w;
                hrB[4*i+0] = vb.x; hrB[4*i+1] = vb.y; hrB[4*i+2] = vb.z; hrB[4*i+3] = vb.w;
            }
        }

        // --- mlp1 + GELU -> MHS ---
        #pragma unroll
        for (int r = 0; r < 2; ++r) {
            int u = d16 + 16 * r;
            const float4* wp = reinterpret_cast<const float4*>(w1 + u * 16);
            float4 w0 = wp[0], w1_ = wp[1], w2_ = wp[2], w3_ = wp[3];
            float bb = mlp_b1[li * 32 + u];
            float aA = bb + dot16(hrA, w0, w1_, w2_, w3_);
            float aB = bb + dot16(hrB, w0, w1_, w2_, w3_);
            sm[MHS + tA * 36 + u] = gelu_exact(aA);
            sm[MHS + tB * 36 + u] = gelu_exact(aB);
        }
        WAVE_SYNC();

        // --- mlp2 + residual ---
        {
            const float4* wp  = reinterpret_cast<const float4*>(w2 + d16 * 32);
            const float4* mA  = reinterpret_cast<const float4*>(&sm[MHS + tA * 36]);
            const float4* mB  = reinterpret_cast<const float4*>(&sm[MHS + tB * 36]);
            float bb = mlp_b2[li * 16 + d16];
            float aA = bb, aB = bb;
            #pragma unroll
            for (int i = 0; i < 8; ++i) {
                float4 w = wp[i];
                float4 va = mA[i], vb = mB[i];
                aA += va.x*w.x + va.y*w.y + va.z*w.z + va.w*w.w;
                aB += vb.x*w.x + vb.y*w.y + vb.z*w.z + vb.w*w.w;
            }
            zA += aA;
            zB += aB;
        }
        WAVE_SYNC();   // MHS/H1/QKV reads done before next layer overwrites
    }

    // ---------- head: LN(cls) -> 2-way linear -> softmax ----------
    if (lane < 16) {
        float cv = ln_norm16(zA, head_ln_g[d16], head_ln_b[d16]);
        float p0 = cv * head_w[d16];
        float p1 = cv * head_w[16 + d16];
        #pragma unroll
        for (int off = 8; off >= 1; off >>= 1) {
            p0 += __shfl_xor(p0, off, 16);
            p1 += __shfl_xor(p1, off, 16);
        }
        if (lane == 0) {
            float l0 = p0 + head_b[0], l1 = p1 + head_b[1];
            float mx = fmaxf(l0, l1);
            float e0 = __expf(l0 - mx), e1 = __expf(l1 - mx);
            float inv = 1.f / (e0 + e1);
            out[b * 2 + 0] = e0 * inv;
            out[b * 2 + 1] = e1 * inv;
        }
    }
}

extern "C" void kernel_launch(void* const* d_in, const int* in_sizes, int n_in,
                              void* d_out, int out_size, void* d_ws, size_t ws_size,
                              hipStream_t stream) {
    (void)n_in; (void)d_ws; (void)ws_size; (void)out_size;
    const float* a0  = (const float*)d_in[0];
    const float* a1  = (const float*)d_in[1];
    const float* a2  = (const float*)d_in[2];
    const float* a3  = (const float*)d_in[3];
    const float* a4  = (const float*)d_in[4];
    const float* a5  = (const float*)d_in[5];
    const float* a6  = (const float*)d_in[6];
    const float* a7  = (const float*)d_in[7];
    const float* a8  = (const float*)d_in[8];
    const float* a9  = (const float*)d_in[9];
    const float* a10 = (const float*)d_in[10];
    const float* a11 = (const float*)d_in[11];
    const float* a12 = (const float*)d_in[12];
    const float* a13 = (const float*)d_in[13];
    const float* a14 = (const float*)d_in[14];
    const float* a15 = (const float*)d_in[15];
    const float* a16 = (const float*)d_in[16];
    const float* a17 = (const float*)d_in[17];
    const float* a18 = (const float*)d_in[18];
    const float* a19 = (const float*)d_in[19];
    const float* a20 = (const float*)d_in[20];
    const float* a21 = (const float*)d_in[21];
    const float* a22 = (const float*)d_in[22];
    const float* a23 = (const float*)d_in[23];
    const float* a24 = (const float*)d_in[24];
    const float* a25 = (const float*)d_in[25];
    const float* a26 = (const float*)d_in[26];
    const float* a27 = (const float*)d_in[27];
    const float* a28 = (const float*)d_in[28];
    const float* a29 = (const float*)d_in[29];
    const float* a30 = (const float*)d_in[30];
    const float* a31 = (const float*)d_in[31];
    const float* a32 = (const float*)d_in[32];

    int Bn = in_sizes[0] / (64 * 125);          // 2048 samples, 1 wave each
    eegnet_vit_fused<<<Bn, TB, 0, stream>>>(
        a0, a1, a2, a3, a4, a5, a6, a7, a8, a9, a10, a11, a12, a13, a14, a15, a16,
        a17, a18, a19, a20, a21, a22, a23, a24, a25, a26, a27, a28, a29, a30, a31, a32,
        (float*)d_out);
}